// Round 6
// baseline (135.327 us; speedup 1.0000x reference)
//
#include <hip/hip_runtime.h>
#include <stdint.h>

#define L_DIM 1024
#define N_DIM 64
#define D_DIM 64
#define O_DIM 1024
#define ND    4096              // slice stride (floats) for x / upfold rows
#define UPAD  72                // padded LDS row in halves (144 B)
#define NT    8                 // O-tiles per team (each 64 wide, team covers 512)

typedef float    floatx16 __attribute__((ext_vector_type(16)));
typedef _Float16 half8    __attribute__((ext_vector_type(8)));
typedef _Float16 h2       __attribute__((ext_vector_type(2)));
typedef __fp16   fp16x2   __attribute__((ext_vector_type(2)));

__device__ __forceinline__ uint32_t pkh2(float a, float b) {
    fp16x2 p = __builtin_amdgcn_cvt_pkrtz(a, b);   // v_cvt_pkrtz_f16_f32
    return __builtin_bit_cast(uint32_t, p);
}

__device__ __forceinline__ half8 mk_frag(uint32_t a, uint32_t b, uint32_t c, uint32_t d) {
    union { uint32_t u[4]; half8 v; } U;
    U.u[0] = a; U.u[1] = b; U.u[2] = c; U.u[3] = d;
    return U.v;
}

// sigmoid(s/8) - 0.5 = 0.5*tanh(s/16), odd poly in v=(s/16)^2, packed fp16.
__device__ __forceinline__ uint32_t psig(float s0, float s1) {
    const h2 HI = {(_Float16)41.6f,        (_Float16)41.6f};
    const h2 LO = {(_Float16)-41.6f,       (_Float16)-41.6f};
    const h2 SC = {(_Float16)0.0625f,      (_Float16)0.0625f};
    const h2 C0 = {(_Float16)0.03099238f,  (_Float16)0.03099238f};
    const h2 C1 = {(_Float16)-0.00842090f, (_Float16)-0.00842090f};
    const h2 C2 = {(_Float16)0.00151845f,  (_Float16)0.00151845f};
    const h2 C3 = {(_Float16)-1.02197e-4f, (_Float16)-1.02197e-4f};
    h2 s = __builtin_bit_cast(h2, pkh2(s0, s1));
    s = __builtin_elementwise_min(s, HI);
    s = __builtin_elementwise_max(s, LO);
    h2 ha = s * SC;
    h2 v  = ha * ha;
    h2 w  = C2 + v * C3;
    w     = C1 + v * w;
    w     = C0 + v * w;
    h2 f  = s * w;
    return __builtin_bit_cast(uint32_t, f);
}

__device__ __forceinline__ void load_tile(const float* ubase, int team, int ot,
                                          int rp, int cq, float* va, float* vb) {
    const float* pr = ubase + (size_t)(team * 512 + ot * 64 + 2 * rp) * ND + 16 * cq;
    #pragma unroll
    for (int j = 0; j < 4; ++j) {
        float4 f = *(const float4*)(pr + 4 * j);
        va[4*j] = f.x; va[4*j+1] = f.y; va[4*j+2] = f.z; va[4*j+3] = f.w;
        float4 g = *(const float4*)(pr + ND + 4 * j);
        vb[4*j] = g.x; vb[4*j+1] = g.y; vb[4*j+2] = g.z; vb[4*j+3] = g.w;
    }
}

__global__ void __launch_bounds__(256, 3)
corr_kernel(const float* __restrict__ x, const float* __restrict__ up,
            float* __restrict__ out)
{
    __shared__ __align__(16) unsigned char smem[36864];
    uint16_t (*Ub)[64][UPAD] = (uint16_t (*)[64][UPAD])smem;            // [2][64][72]
    uint16_t (*Ut)[64][UPAD] = (uint16_t (*)[64][UPAD])(smem + 18432);  // [2][64][72]
    float    (*Fred)[2][2][32][16] = (float (*)[2][2][32][16])smem;     // epilogue overlay
    float    (*Xs)[68] = (float (*)[68])smem;                           // init overlay, 17.4 KB

    const int tid  = threadIdx.x;
    const int lane = tid & 63;
    const int wid  = tid >> 6;
    const int l31  = lane & 31;
    const int h    = lane >> 5;          // wave half
    const int team = wid >> 1;           // O-range: team*512 .. +512
    const int wrow = wid & 1;            // which 32-row group of the 64-row L-tile
    const int ttid = tid & 127;          // id within team
    const int rp   = ttid & 31;          // staging row-pair (rows 2rp, 2rp+1)
    const int cq   = ttid >> 5;          // staging col group (16 cols)
    const int n    = blockIdx.x;         // XCD swizzle: same n -> same XCD
    const int lb   = blockIdx.y;
    const int lw   = lb * 64 + wrow * 32 + l31;

    const float* ubase = up + (size_t)n * D_DIM;

    // issue U tile 0/1 loads first (longest latency path)
    float va[2][16], vb[2][16];
    load_tile(ubase, team, 0, rp, cq, va[0], vb[0]);
    load_tile(ubase, team, 1, rp, cq, va[1], vb[1]);

    // ---- phase 0: coalesced X tile -> LDS fp32, then build Xf frags ----
    half8 Xf[4];
    {
        const int xr = tid >> 2;               // row within L-tile (0..63)
        const int xc = tid & 3;                // float4 column phase
        const float* xsrc = x + (size_t)(lb * 64 + xr) * ND + n * D_DIM;
        #pragma unroll
        for (int j = 0; j < 4; ++j) {
            float4 f = *(const float4*)(xsrc + 4 * (xc + 4 * j));
            *(float4*)&Xs[xr][4 * (xc + 4 * j)] = f;
        }
        __syncthreads();
        const int rl = wrow * 32 + l31;
        #pragma unroll
        for (int kk = 0; kk < 4; ++kk) {
            float4 f1 = *(const float4*)&Xs[rl][16 * kk + 8 * h];
            float4 f2 = *(const float4*)&Xs[rl][16 * kk + 8 * h + 4];
            Xf[kk] = mk_frag(pkh2(f1.x, f1.y), pkh2(f1.z, f1.w),
                             pkh2(f2.x, f2.y), pkh2(f2.z, f2.w));
        }
        __syncthreads();   // protect Xs before Ub staging overwrites it
    }

    floatx16 F0, F1;   // F^T partial accumulators, d 0..31 / 32..63
    #pragma unroll
    for (int i = 0; i < 16; ++i) { F0[i] = 0.0f; F1[i] = 0.0f; }

    #pragma unroll
    for (int ot = 0; ot < NT; ++ot) {
        const int b = ot & 1;
        // ---- stage registers -> LDS (fp16): Ub rows + Ut transpose ----
        *(uint4*)&Ub[team][2*rp][16*cq] =
            make_uint4(pkh2(va[b][0],va[b][1]),  pkh2(va[b][2],va[b][3]),
                       pkh2(va[b][4],va[b][5]),  pkh2(va[b][6],va[b][7]));
        *(uint4*)&Ub[team][2*rp][16*cq + 8] =
            make_uint4(pkh2(va[b][8],va[b][9]),  pkh2(va[b][10],va[b][11]),
                       pkh2(va[b][12],va[b][13]),pkh2(va[b][14],va[b][15]));
        *(uint4*)&Ub[team][2*rp+1][16*cq] =
            make_uint4(pkh2(vb[b][0],vb[b][1]),  pkh2(vb[b][2],vb[b][3]),
                       pkh2(vb[b][4],vb[b][5]),  pkh2(vb[b][6],vb[b][7]));
        *(uint4*)&Ub[team][2*rp+1][16*cq + 8] =
            make_uint4(pkh2(vb[b][8],vb[b][9]),  pkh2(vb[b][10],vb[b][11]),
                       pkh2(vb[b][12],vb[b][13]),pkh2(vb[b][14],vb[b][15]));
        #pragma unroll
        for (int j = 0; j < 16; ++j)   // Ut[d][o-pair]: banks (4j+rp)%32, 2/bank = free
            *(uint32_t*)&Ut[team][16*cq + j][2*rp] = pkh2(va[b][j], vb[b][j]);
        __syncthreads();

        // distance-2 prefetch into the just-consumed register set
        if (ot + 2 < NT)
            load_tile(ubase, team, ot + 2, rp, cq, va[b], vb[b]);

        // ---- GEMM1: S^T = U * X^T   (M=o-local, N=l, K=d) ----
        floatx16 S0, S1;
        #pragma unroll
        for (int i = 0; i < 16; ++i) { S0[i] = 0.0f; S1[i] = 0.0f; }
        #pragma unroll
        for (int kk = 0; kk < 4; ++kk) {
            half8 A0 = *(const half8*)&Ub[team][l31][16 * kk + 8 * h];
            half8 A1 = *(const half8*)&Ub[team][32 + l31][16 * kk + 8 * h];
            S0 = __builtin_amdgcn_mfma_f32_32x32x16_f16(A0, Xf[kk], S0, 0, 0, 0);
            S1 = __builtin_amdgcn_mfma_f32_32x32x16_f16(A1, Xf[kk], S1, 0, 0, 0);
        }

        // ---- sigmoid weights: packed-fp16 odd polynomial ----
        uint32_t P[16];
        #pragma unroll
        for (int m = 0; m < 8; ++m) P[m]     = psig(S0[2*m], S0[2*m+1]);
        #pragma unroll
        for (int m = 0; m < 8; ++m) P[8 + m] = psig(S1[2*m], S1[2*m+1]);

        // ---- GEMM2: F^T += U^T * W — shuffles hoisted ahead of MFMA chain ----
        uint32_t R[8];
        #pragma unroll
        for (int c = 0; c < 4; ++c) {
            const uint32_t* Q = P + (c >> 1) * 8;
            const int t4 = (c & 1) * 4;
            R[2*c]   = __shfl_xor(h ? Q[t4]     : Q[t4 + 2], 32);
            R[2*c+1] = __shfl_xor(h ? Q[t4 + 1] : Q[t4 + 3], 32);
        }
        #pragma unroll
        for (int c = 0; c < 4; ++c) {
            const uint32_t* Q = P + (c >> 1) * 8;
            const int t4 = (c & 1) * 4;
            half8 B = h ? mk_frag(R[2*c], R[2*c+1], Q[t4 + 2], Q[t4 + 3])
                        : mk_frag(Q[t4], Q[t4 + 1], R[2*c], R[2*c+1]);
            half8 A0 = *(const half8*)&Ut[team][l31][16 * c + 8 * h];
            half8 A1 = *(const half8*)&Ut[team][32 + l31][16 * c + 8 * h];
            F0 = __builtin_amdgcn_mfma_f32_32x32x16_f16(A0, B, F0, 0, 0, 0);
            F1 = __builtin_amdgcn_mfma_f32_32x32x16_f16(A1, B, F1, 0, 0, 0);
        }
        __syncthreads();
    }

    // ---- cross-team reduction: exchange one accumulator half each ----
    {
        float* dst = &Fred[team][wrow][h][l31][0];
        const floatx16& Fexp = team ? F0 : F1;
        #pragma unroll
        for (int q = 0; q < 4; ++q)
            *(float4*)(dst + 4*q) = make_float4(Fexp[4*q], Fexp[4*q+1], Fexp[4*q+2], Fexp[4*q+3]);
    }
    __syncthreads();

    float* op = out + (size_t)lw * ND + n * D_DIM;
    if (team == 0) {
        const float* src = &Fred[1][wrow][h][l31][0];
        #pragma unroll
        for (int q = 0; q < 4; ++q) {
            float4 r = *(const float4*)(src + 4*q);
            float4 a; a.x = F0[4*q]   + r.x; a.y = F0[4*q+1] + r.y;
                      a.z = F0[4*q+2] + r.z; a.w = F0[4*q+3] + r.w;
            *(float4*)(op + 8*q + 4*h) = a;               // d 0..31
        }
    } else {
        const float* src = &Fred[0][wrow][h][l31][0];
        #pragma unroll
        for (int q = 0; q < 4; ++q) {
            float4 r = *(const float4*)(src + 4*q);
            float4 a; a.x = F1[4*q]   + r.x; a.y = F1[4*q+1] + r.y;
                      a.z = F1[4*q+2] + r.z; a.w = F1[4*q+3] + r.w;
            *(float4*)(op + 32 + 8*q + 4*h) = a;          // d 32..63
        }
    }
}

extern "C" void kernel_launch(void* const* d_in, const int* in_sizes, int n_in,
                              void* d_out, int out_size, void* d_ws, size_t ws_size,
                              hipStream_t stream)
{
    const float* x  = (const float*)d_in[0];
    const float* up = (const float*)d_in[1];
    float* out      = (float*)d_out;
    dim3 grid(N_DIM, L_DIM / 64);   // x = n (XCD affinity), y = L-tile
    corr_kernel<<<grid, dim3(256), 0, stream>>>(x, up, out);
}

// Round 7
// 109.474 us; speedup vs baseline: 1.2361x; 1.2361x over previous
//
#include <hip/hip_runtime.h>
#include <stdint.h>

#define L_DIM 1024
#define N_DIM 64
#define D_DIM 64
#define O_DIM 1024
#define ND    4096              // slice stride (floats) for x / upfold rows
#define UPAD  72                // padded LDS row in halves (144 B)
#define NT    8                 // O-tiles per team (each 64 wide, team covers 512)

typedef float    floatx16 __attribute__((ext_vector_type(16)));
typedef _Float16 half8    __attribute__((ext_vector_type(8)));
typedef _Float16 h2       __attribute__((ext_vector_type(2)));
typedef __fp16   fp16x2   __attribute__((ext_vector_type(2)));

__device__ __forceinline__ uint32_t pkh2(float a, float b) {
    fp16x2 p = __builtin_amdgcn_cvt_pkrtz(a, b);   // v_cvt_pkrtz_f16_f32
    return __builtin_bit_cast(uint32_t, p);
}

__device__ __forceinline__ half8 mk_frag(uint32_t a, uint32_t b, uint32_t c, uint32_t d) {
    union { uint32_t u[4]; half8 v; } U;
    U.u[0] = a; U.u[1] = b; U.u[2] = c; U.u[3] = d;
    return U.v;
}

// sigmoid(s/8) - 0.5 = 0.5*tanh(s/16), odd poly in v=(s/16)^2, packed fp16.
__device__ __forceinline__ uint32_t psig(float s0, float s1) {
    const h2 HI = {(_Float16)41.6f,        (_Float16)41.6f};
    const h2 LO = {(_Float16)-41.6f,       (_Float16)-41.6f};
    const h2 SC = {(_Float16)0.0625f,      (_Float16)0.0625f};
    const h2 C0 = {(_Float16)0.03099238f,  (_Float16)0.03099238f};
    const h2 C1 = {(_Float16)-0.00842090f, (_Float16)-0.00842090f};
    const h2 C2 = {(_Float16)0.00151845f,  (_Float16)0.00151845f};
    const h2 C3 = {(_Float16)-1.02197e-4f, (_Float16)-1.02197e-4f};
    h2 s = __builtin_bit_cast(h2, pkh2(s0, s1));
    s = __builtin_elementwise_min(s, HI);
    s = __builtin_elementwise_max(s, LO);
    h2 ha = s * SC;
    h2 v  = ha * ha;
    h2 w  = C2 + v * C3;
    w     = C1 + v * w;
    w     = C0 + v * w;
    h2 f  = s * w;
    return __builtin_bit_cast(uint32_t, f);
}

__device__ __forceinline__ void load_tile(const float* ubase, int team, int ot,
                                          int rp, int cq, float* va, float* vb) {
    const float* pr = ubase + (size_t)(team * 512 + ot * 64 + 2 * rp) * ND + 16 * cq;
    #pragma unroll
    for (int j = 0; j < 4; ++j) {
        float4 f = *(const float4*)(pr + 4 * j);
        va[4*j] = f.x; va[4*j+1] = f.y; va[4*j+2] = f.z; va[4*j+3] = f.w;
        float4 g = *(const float4*)(pr + ND + 4 * j);
        vb[4*j] = g.x; vb[4*j+1] = g.y; vb[4*j+2] = g.z; vb[4*j+3] = g.w;
    }
}

__global__ void __launch_bounds__(256, 4)
corr_kernel(const float* __restrict__ x, const float* __restrict__ up,
            float* __restrict__ out)
{
    __shared__ __align__(16) unsigned char smem[36864];
    uint16_t (*Ub)[64][UPAD] = (uint16_t (*)[64][UPAD])smem;            // [2][64][72]
    uint16_t (*Ut)[64][UPAD] = (uint16_t (*)[64][UPAD])(smem + 18432);  // [2][64][72]
    float    (*Fred)[2][2][32][16] = (float (*)[2][2][32][16])smem;     // epilogue overlay
    float    (*Xs)[68] = (float (*)[68])smem;                           // init overlay, 17.4 KB

    const int tid  = threadIdx.x;
    const int lane = tid & 63;
    const int wid  = tid >> 6;
    const int l31  = lane & 31;
    const int h    = lane >> 5;          // wave half
    const int team = wid >> 1;           // O-range: team*512 .. +512
    const int wrow = wid & 1;            // which 32-row group of the 64-row L-tile
    const int ttid = tid & 127;          // id within team
    const int rp   = ttid & 31;          // staging row-pair (rows 2rp, 2rp+1)
    const int cq   = ttid >> 5;          // staging col group (16 cols)
    const int n    = blockIdx.x;         // XCD swizzle: same n -> same XCD
    const int lb   = blockIdx.y;
    const int lw   = lb * 64 + wrow * 32 + l31;

    const float* ubase = up + (size_t)n * D_DIM;

    // issue U tile 0 load first (longest latency path); single register buffer
    float va[16], vb[16];
    load_tile(ubase, team, 0, rp, cq, va, vb);

    // ---- phase 0: coalesced X tile -> LDS fp32, then build Xf frags ----
    half8 Xf[4];
    {
        const int xr = tid >> 2;               // row within L-tile (0..63)
        const int xc = tid & 3;                // float4 column phase
        const float* xsrc = x + (size_t)(lb * 64 + xr) * ND + n * D_DIM;
        #pragma unroll
        for (int j = 0; j < 4; ++j) {
            float4 f = *(const float4*)(xsrc + 4 * (xc + 4 * j));
            *(float4*)&Xs[xr][4 * (xc + 4 * j)] = f;
        }
        __syncthreads();
        const int rl = wrow * 32 + l31;
        #pragma unroll
        for (int kk = 0; kk < 4; ++kk) {
            float4 f1 = *(const float4*)&Xs[rl][16 * kk + 8 * h];
            float4 f2 = *(const float4*)&Xs[rl][16 * kk + 8 * h + 4];
            Xf[kk] = mk_frag(pkh2(f1.x, f1.y), pkh2(f1.z, f1.w),
                             pkh2(f2.x, f2.y), pkh2(f2.z, f2.w));
        }
        __syncthreads();   // protect Xs before Ub staging overwrites it
    }

    floatx16 F0, F1;   // F^T partial accumulators, d 0..31 / 32..63
    #pragma unroll
    for (int i = 0; i < 16; ++i) { F0[i] = 0.0f; F1[i] = 0.0f; }

    for (int ot = 0; ot < NT; ++ot) {
        // ---- stage registers -> LDS (fp16): Ub rows + Ut transpose ----
        *(uint4*)&Ub[team][2*rp][16*cq] =
            make_uint4(pkh2(va[0],va[1]),  pkh2(va[2],va[3]),
                       pkh2(va[4],va[5]),  pkh2(va[6],va[7]));
        *(uint4*)&Ub[team][2*rp][16*cq + 8] =
            make_uint4(pkh2(va[8],va[9]),  pkh2(va[10],va[11]),
                       pkh2(va[12],va[13]),pkh2(va[14],va[15]));
        *(uint4*)&Ub[team][2*rp+1][16*cq] =
            make_uint4(pkh2(vb[0],vb[1]),  pkh2(vb[2],vb[3]),
                       pkh2(vb[4],vb[5]),  pkh2(vb[6],vb[7]));
        *(uint4*)&Ub[team][2*rp+1][16*cq + 8] =
            make_uint4(pkh2(vb[8],vb[9]),  pkh2(vb[10],vb[11]),
                       pkh2(vb[12],vb[13]),pkh2(vb[14],vb[15]));
        #pragma unroll
        for (int j = 0; j < 16; ++j)   // Ut[d][o-pair]: banks (4j+rp)%32, 2/bank = free
            *(uint32_t*)&Ut[team][16*cq + j][2*rp] = pkh2(va[j], vb[j]);
        __syncthreads();

        // distance-1 prefetch into the just-consumed registers
        if (ot + 1 < NT)
            load_tile(ubase, team, ot + 1, rp, cq, va, vb);

        // ---- GEMM1: S^T = U * X^T   (M=o-local, N=l, K=d) ----
        floatx16 S0, S1;
        #pragma unroll
        for (int i = 0; i < 16; ++i) { S0[i] = 0.0f; S1[i] = 0.0f; }
        #pragma unroll
        for (int kk = 0; kk < 4; ++kk) {
            half8 A0 = *(const half8*)&Ub[team][l31][16 * kk + 8 * h];
            half8 A1 = *(const half8*)&Ub[team][32 + l31][16 * kk + 8 * h];
            S0 = __builtin_amdgcn_mfma_f32_32x32x16_f16(A0, Xf[kk], S0, 0, 0, 0);
            S1 = __builtin_amdgcn_mfma_f32_32x32x16_f16(A1, Xf[kk], S1, 0, 0, 0);
        }

        // ---- sigmoid weights: packed-fp16 odd polynomial ----
        uint32_t P[16];
        #pragma unroll
        for (int m = 0; m < 8; ++m) P[m]     = psig(S0[2*m], S0[2*m+1]);
        #pragma unroll
        for (int m = 0; m < 8; ++m) P[8 + m] = psig(S1[2*m], S1[2*m+1]);

        // ---- GEMM2: F^T += U^T * W — shuffles hoisted ahead of MFMA chain ----
        uint32_t R[8];
        #pragma unroll
        for (int c = 0; c < 4; ++c) {
            const uint32_t* Q = P + (c >> 1) * 8;
            const int t4 = (c & 1) * 4;
            R[2*c]   = __shfl_xor(h ? Q[t4]     : Q[t4 + 2], 32);
            R[2*c+1] = __shfl_xor(h ? Q[t4 + 1] : Q[t4 + 3], 32);
        }
        #pragma unroll
        for (int c = 0; c < 4; ++c) {
            const uint32_t* Q = P + (c >> 1) * 8;
            const int t4 = (c & 1) * 4;
            half8 B = h ? mk_frag(R[2*c], R[2*c+1], Q[t4 + 2], Q[t4 + 3])
                        : mk_frag(Q[t4], Q[t4 + 1], R[2*c], R[2*c+1]);
            half8 A0 = *(const half8*)&Ut[team][l31][16 * c + 8 * h];
            half8 A1 = *(const half8*)&Ut[team][32 + l31][16 * c + 8 * h];
            F0 = __builtin_amdgcn_mfma_f32_32x32x16_f16(A0, B, F0, 0, 0, 0);
            F1 = __builtin_amdgcn_mfma_f32_32x32x16_f16(A1, B, F1, 0, 0, 0);
        }
        __syncthreads();
    }

    // ---- cross-team reduction: exchange one accumulator half each ----
    {
        float* dst = &Fred[team][wrow][h][l31][0];
        const floatx16& Fexp = team ? F0 : F1;
        #pragma unroll
        for (int q = 0; q < 4; ++q)
            *(float4*)(dst + 4*q) = make_float4(Fexp[4*q], Fexp[4*q+1], Fexp[4*q+2], Fexp[4*q+3]);
    }
    __syncthreads();

    float* op = out + (size_t)lw * ND + n * D_DIM;
    if (team == 0) {
        const float* src = &Fred[1][wrow][h][l31][0];
        #pragma unroll
        for (int q = 0; q < 4; ++q) {
            float4 r = *(const float4*)(src + 4*q);
            float4 a; a.x = F0[4*q]   + r.x; a.y = F0[4*q+1] + r.y;
                      a.z = F0[4*q+2] + r.z; a.w = F0[4*q+3] + r.w;
            *(float4*)(op + 8*q + 4*h) = a;               // d 0..31
        }
    } else {
        const float* src = &Fred[0][wrow][h][l31][0];
        #pragma unroll
        for (int q = 0; q < 4; ++q) {
            float4 r = *(const float4*)(src + 4*q);
            float4 a; a.x = F1[4*q]   + r.x; a.y = F1[4*q+1] + r.y;
                      a.z = F1[4*q+2] + r.z; a.w = F1[4*q+3] + r.w;
            *(float4*)(op + 32 + 8*q + 4*h) = a;          // d 32..63
        }
    }
}

extern "C" void kernel_launch(void* const* d_in, const int* in_sizes, int n_in,
                              void* d_out, int out_size, void* d_ws, size_t ws_size,
                              hipStream_t stream)
{
    const float* x  = (const float*)d_in[0];
    const float* up = (const float*)d_in[1];
    float* out      = (float*)d_out;
    dim3 grid(N_DIM, L_DIM / 64);   // x = n (XCD affinity), y = L-tile
    corr_kernel<<<grid, dim3(256), 0, stream>>>(x, up, out);
}

// Round 8
// 104.078 us; speedup vs baseline: 1.3002x; 1.0518x over previous
//
#include <hip/hip_runtime.h>
#include <stdint.h>

#define L_DIM 1024
#define N_DIM 64
#define D_DIM 64
#define O_DIM 1024
#define ND    4096              // slice stride (floats) for x / upfold rows
#define NT    8                 // O-tiles per team (each 64 wide, team covers 512)

typedef float    floatx16 __attribute__((ext_vector_type(16)));
typedef _Float16 half8    __attribute__((ext_vector_type(8)));
typedef _Float16 h2       __attribute__((ext_vector_type(2)));
typedef __fp16   fp16x2   __attribute__((ext_vector_type(2)));

__device__ __forceinline__ uint32_t pkh2(float a, float b) {
    fp16x2 p = __builtin_amdgcn_cvt_pkrtz(a, b);   // v_cvt_pkrtz_f16_f32
    return __builtin_bit_cast(uint32_t, p);
}

__device__ __forceinline__ half8 mk_frag(uint32_t a, uint32_t b, uint32_t c, uint32_t d) {
    union { uint32_t u[4]; half8 v; } U;
    U.u[0] = a; U.u[1] = b; U.u[2] = c; U.u[3] = d;
    return U.v;
}

// sigmoid(s/8) - 0.5 = 0.5*tanh(s/16), odd poly in v=(s/16)^2, packed fp16.
__device__ __forceinline__ uint32_t psig(float s0, float s1) {
    const h2 HI = {(_Float16)41.6f,        (_Float16)41.6f};
    const h2 LO = {(_Float16)-41.6f,       (_Float16)-41.6f};
    const h2 SC = {(_Float16)0.0625f,      (_Float16)0.0625f};
    const h2 C0 = {(_Float16)0.03099238f,  (_Float16)0.03099238f};
    const h2 C1 = {(_Float16)-0.00842090f, (_Float16)-0.00842090f};
    const h2 C2 = {(_Float16)0.00151845f,  (_Float16)0.00151845f};
    const h2 C3 = {(_Float16)-1.02197e-4f, (_Float16)-1.02197e-4f};
    h2 s = __builtin_bit_cast(h2, pkh2(s0, s1));
    s = __builtin_elementwise_min(s, HI);
    s = __builtin_elementwise_max(s, LO);
    h2 ha = s * SC;
    h2 v  = ha * ha;
    h2 w  = C2 + v * C3;
    w     = C1 + v * w;
    w     = C0 + v * w;
    h2 f  = s * w;
    return __builtin_bit_cast(uint32_t, f);
}

// Coalesced U tile load: thread (g,c) takes rows 2g+16j (va) / +1 (vb), cols 4c..4c+3.
// Per wave-instr: 16 lanes cover one contiguous 256B row -> 16 cache lines/instr.
__device__ __forceinline__ void load_tile(const float* ubase, int team, int ot,
                                          int g, int c, float4* va, float4* vb) {
    const float* pr = ubase + (size_t)(team * 512 + ot * 64 + 2 * g) * ND + 4 * c;
    #pragma unroll
    for (int j = 0; j < 4; ++j) {
        va[j] = *(const float4*)(pr + (size_t)(16 * j) * ND);
        vb[j] = *(const float4*)(pr + (size_t)(16 * j) * ND + ND);
    }
}

__global__ void __launch_bounds__(256, 4)
corr_kernel(const float* __restrict__ x, const float* __restrict__ up,
            float* __restrict__ out)
{
    __shared__ __align__(16) unsigned char smem[36864];
    uint16_t (*Ub)[64][72]  = (uint16_t (*)[64][72])smem;               // 2 x 9216 B
    uint32_t (*Ut2)[32][68] = (uint32_t (*)[32][68])(smem + 18432);     // 2 x 8704 B: [o-pair][d]
    float    (*Fred)[2][2][32][16] = (float (*)[2][2][32][16])smem;     // epilogue overlay 16 KB
    float    (*Xs)[68] = (float (*)[68])smem;                           // init overlay 17.4 KB

    const int tid  = threadIdx.x;
    const int lane = tid & 63;
    const int wid  = tid >> 6;
    const int l31  = lane & 31;
    const int h    = lane >> 5;          // wave half
    const int team = wid >> 1;           // O-range: team*512 .. +512
    const int wrow = wid & 1;            // which 32-row group of the 64-row L-tile
    const int ttid = tid & 127;          // id within team
    const int c    = ttid & 15;          // col quad: d = 4c..4c+3
    const int g    = ttid >> 4;          // 0..7: rows 2g+16j
    const int n    = blockIdx.x;         // XCD swizzle: same n -> same XCD
    const int lb   = blockIdx.y;
    const int lw   = lb * 64 + wrow * 32 + l31;

    const float* ubase = up + (size_t)n * D_DIM;

    // issue U tile 0 load first (longest latency path)
    float4 va[4], vb[4];
    load_tile(ubase, team, 0, g, c, va, vb);

    // ---- phase 0: coalesced X tile -> LDS fp32, then build Xf frags ----
    half8 Xf[4];
    {
        const int xr = tid >> 2;               // row within L-tile (0..63)
        const int xc = tid & 3;                // float4 column phase
        const float* xsrc = x + (size_t)(lb * 64 + xr) * ND + n * D_DIM;
        #pragma unroll
        for (int j = 0; j < 4; ++j) {
            float4 f = *(const float4*)(xsrc + 4 * (xc + 4 * j));
            *(float4*)&Xs[xr][4 * (xc + 4 * j)] = f;
        }
        __syncthreads();
        const int rl = wrow * 32 + l31;
        #pragma unroll
        for (int kk = 0; kk < 4; ++kk) {
            float4 f1 = *(const float4*)&Xs[rl][16 * kk + 8 * h];
            float4 f2 = *(const float4*)&Xs[rl][16 * kk + 8 * h + 4];
            Xf[kk] = mk_frag(pkh2(f1.x, f1.y), pkh2(f1.z, f1.w),
                             pkh2(f2.x, f2.y), pkh2(f2.z, f2.w));
        }
        __syncthreads();   // protect Xs before tile-0 staging overwrites it
    }

    floatx16 F0, F1;   // F^T partial accumulators, d 0..31 / 32..63
    #pragma unroll
    for (int i = 0; i < 16; ++i) { F0[i] = 0.0f; F1[i] = 0.0f; }

    for (int ot = 0; ot < NT; ++ot) {
        // ---- stage registers -> LDS fp16: Ub rows (b64) + Ut2 o-pair rows (b128) ----
        #pragma unroll
        for (int j = 0; j < 4; ++j) {
            uint2 ea = make_uint2(pkh2(va[j].x, va[j].y), pkh2(va[j].z, va[j].w));
            uint2 eb = make_uint2(pkh2(vb[j].x, vb[j].y), pkh2(vb[j].z, vb[j].w));
            *(uint2*)&Ub[team][2*g + 16*j][4*c]     = ea;
            *(uint2*)&Ub[team][2*g + 16*j + 1][4*c] = eb;
            uint4 et = make_uint4(pkh2(va[j].x, vb[j].x), pkh2(va[j].y, vb[j].y),
                                  pkh2(va[j].z, vb[j].z), pkh2(va[j].w, vb[j].w));
            *(uint4*)&Ut2[team][g + 8*j][4*c] = et;
        }
        __syncthreads();

        // distance-1 prefetch into the just-consumed registers
        if (ot + 1 < NT)
            load_tile(ubase, team, ot + 1, g, c, va, vb);

        // ---- GEMM1: S^T = U * X^T   (M=o-local, N=l, K=d) ----
        floatx16 S0, S1;
        #pragma unroll
        for (int i = 0; i < 16; ++i) { S0[i] = 0.0f; S1[i] = 0.0f; }
        #pragma unroll
        for (int kk = 0; kk < 4; ++kk) {
            half8 A0 = *(const half8*)&Ub[team][l31][16 * kk + 8 * h];
            half8 A1 = *(const half8*)&Ub[team][32 + l31][16 * kk + 8 * h];
            S0 = __builtin_amdgcn_mfma_f32_32x32x16_f16(A0, Xf[kk], S0, 0, 0, 0);
            S1 = __builtin_amdgcn_mfma_f32_32x32x16_f16(A1, Xf[kk], S1, 0, 0, 0);
        }

        // ---- sigmoid weights: packed-fp16 odd polynomial ----
        uint32_t P[16];
        #pragma unroll
        for (int m = 0; m < 8; ++m) P[m]     = psig(S0[2*m], S0[2*m+1]);
        #pragma unroll
        for (int m = 0; m < 8; ++m) P[8 + m] = psig(S1[2*m], S1[2*m+1]);

        // ---- GEMM2: F^T += U^T * W — shuffles hoisted ahead of MFMA chain ----
        uint32_t R[8];
        #pragma unroll
        for (int c2 = 0; c2 < 4; ++c2) {
            const uint32_t* Q = P + (c2 >> 1) * 8;
            const int t4 = (c2 & 1) * 4;
            R[2*c2]   = __shfl_xor(h ? Q[t4]     : Q[t4 + 2], 32);
            R[2*c2+1] = __shfl_xor(h ? Q[t4 + 1] : Q[t4 + 3], 32);
        }
        #pragma unroll
        for (int c2 = 0; c2 < 4; ++c2) {
            const uint32_t* Q = P + (c2 >> 1) * 8;
            const int t4 = (c2 & 1) * 4;
            half8 B = h ? mk_frag(R[2*c2], R[2*c2+1], Q[t4 + 2], Q[t4 + 3])
                        : mk_frag(Q[t4], Q[t4 + 1], R[2*c2], R[2*c2+1]);
            // A-frags: column-gather of Ut2 (bank-spread: op*68 + d, 2-way = free)
            const int opb = 8 * c2 + 4 * h;
            const uint32_t* utp = &Ut2[team][0][0];
            uint32_t a0[4], a1[4];
            #pragma unroll
            for (int k = 0; k < 4; ++k) {
                a0[k] = utp[(opb + k) * 68 + l31];
                a1[k] = utp[(opb + k) * 68 + 32 + l31];
            }
            half8 A0 = mk_frag(a0[0], a0[1], a0[2], a0[3]);
            half8 A1 = mk_frag(a1[0], a1[1], a1[2], a1[3]);
            F0 = __builtin_amdgcn_mfma_f32_32x32x16_f16(A0, B, F0, 0, 0, 0);
            F1 = __builtin_amdgcn_mfma_f32_32x32x16_f16(A1, B, F1, 0, 0, 0);
        }
        __syncthreads();
    }

    // ---- cross-team reduction: exchange one accumulator half each ----
    {
        float* dst = &Fred[team][wrow][h][l31][0];
        const floatx16& Fexp = team ? F0 : F1;
        #pragma unroll
        for (int q = 0; q < 4; ++q)
            *(float4*)(dst + 4*q) = make_float4(Fexp[4*q], Fexp[4*q+1], Fexp[4*q+2], Fexp[4*q+3]);
    }
    __syncthreads();

    float* op = out + (size_t)lw * ND + n * D_DIM;
    if (team == 0) {
        const float* src = &Fred[1][wrow][h][l31][0];
        #pragma unroll
        for (int q = 0; q < 4; ++q) {
            float4 r = *(const float4*)(src + 4*q);
            float4 a; a.x = F0[4*q]   + r.x; a.y = F0[4*q+1] + r.y;
                      a.z = F0[4*q+2] + r.z; a.w = F0[4*q+3] + r.w;
            *(float4*)(op + 8*q + 4*h) = a;               // d 0..31
        }
    } else {
        const float* src = &Fred[0][wrow][h][l31][0];
        #pragma unroll
        for (int q = 0; q < 4; ++q) {
            float4 r = *(const float4*)(src + 4*q);
            float4 a; a.x = F1[4*q]   + r.x; a.y = F1[4*q+1] + r.y;
                      a.z = F1[4*q+2] + r.z; a.w = F1[4*q+3] + r.w;
            *(float4*)(op + 32 + 8*q + 4*h) = a;          // d 32..63
        }
    }
}

extern "C" void kernel_launch(void* const* d_in, const int* in_sizes, int n_in,
                              void* d_out, int out_size, void* d_ws, size_t ws_size,
                              hipStream_t stream)
{
    const float* x  = (const float*)d_in[0];
    const float* up = (const float*)d_in[1];
    float* out      = (float*)d_out;
    dim3 grid(N_DIM, L_DIM / 64);   // x = n (XCD affinity), y = L-tile
    corr_kernel<<<grid, dim3(256), 0, stream>>>(x, up, out);
}

// Round 9
// 101.207 us; speedup vs baseline: 1.3371x; 1.0284x over previous
//
#include <hip/hip_runtime.h>
#include <stdint.h>

#define L_DIM 1024
#define N_DIM 64
#define D_DIM 64
#define O_DIM 1024
#define ND    4096              // slice stride (floats) for x / upfold rows
#define NT    16                // O tiles (64 wide), full O per block

typedef float    floatx16 __attribute__((ext_vector_type(16)));
typedef _Float16 half8    __attribute__((ext_vector_type(8)));
typedef _Float16 h2       __attribute__((ext_vector_type(2)));
typedef __fp16   fp16x2   __attribute__((ext_vector_type(2)));

#define BUF_STRIDE 17920        // per-buffer: Ub 9216 B + Ut2 8704 B

__device__ __forceinline__ uint32_t pkh2(float a, float b) {
    fp16x2 p = __builtin_amdgcn_cvt_pkrtz(a, b);   // v_cvt_pkrtz_f16_f32
    return __builtin_bit_cast(uint32_t, p);
}

__device__ __forceinline__ half8 mk_frag(uint32_t a, uint32_t b, uint32_t c, uint32_t d) {
    union { uint32_t u[4]; half8 v; } U;
    U.u[0] = a; U.u[1] = b; U.u[2] = c; U.u[3] = d;
    return U.v;
}

// sigmoid(s/8) - 0.5 = 0.5*tanh(s/16), odd poly in v=(s/16)^2, packed fp16.
__device__ __forceinline__ uint32_t psig(float s0, float s1) {
    const h2 HI = {(_Float16)41.6f,        (_Float16)41.6f};
    const h2 LO = {(_Float16)-41.6f,       (_Float16)-41.6f};
    const h2 SC = {(_Float16)0.0625f,      (_Float16)0.0625f};
    const h2 C0 = {(_Float16)0.03099238f,  (_Float16)0.03099238f};
    const h2 C1 = {(_Float16)-0.00842090f, (_Float16)-0.00842090f};
    const h2 C2 = {(_Float16)0.00151845f,  (_Float16)0.00151845f};
    const h2 C3 = {(_Float16)-1.02197e-4f, (_Float16)-1.02197e-4f};
    h2 s = __builtin_bit_cast(h2, pkh2(s0, s1));
    s = __builtin_elementwise_min(s, HI);
    s = __builtin_elementwise_max(s, LO);
    h2 ha = s * SC;
    h2 v  = ha * ha;
    h2 w  = C2 + v * C3;
    w     = C1 + v * w;
    w     = C0 + v * w;
    h2 f  = s * w;
    return __builtin_bit_cast(uint32_t, f);
}

// Coalesced U tile load: thread (r8 = tid>>4, c = tid&15) takes rows 2*r8+32j (va)
// and +1 (vb), cols 4c..4c+3.  Per wave-instr: 4 rows x 256B = 16 cache lines.
__device__ __forceinline__ void load_tile(const float* ubase, int ot,
                                          int r8, int c, float4* va, float4* vb) {
    const float* pr = ubase + (size_t)(ot * 64 + 2 * r8) * ND + 4 * c;
    #pragma unroll
    for (int j = 0; j < 2; ++j) {
        va[j] = *(const float4*)(pr + (size_t)(32 * j) * ND);
        vb[j] = *(const float4*)(pr + (size_t)(32 * j) * ND + ND);
    }
}

__global__ void __launch_bounds__(256, 2)
corr_kernel(const float* __restrict__ x, const float* __restrict__ up,
            float* __restrict__ out)
{
    __shared__ __align__(16) unsigned char smem[2 * BUF_STRIDE];

    const int tid  = threadIdx.x;
    const int lane = tid & 63;
    const int wid  = tid >> 6;
    const int l31  = lane & 31;
    const int h    = lane >> 5;          // wave half
    const int r8   = tid >> 4;           // staging row-group (0..15)
    const int c    = tid & 15;           // staging col quad: d = 4c..4c+3
    const int n    = blockIdx.x;         // XCD swizzle: same n -> same XCD
    const int lb   = blockIdx.y;
    const int lw   = lb * 128 + wid * 32 + l31;   // this lane's l row

    const float* ubase = up + (size_t)n * D_DIM;

    // issue U tile 0 load first (longest latency path)
    float4 va[2], vb[2];
    load_tile(ubase, 0, r8, c, va, vb);

    // ---- phase 0: coalesced X tile (128 rows) -> LDS fp32, build Xf frags ----
    half8 Xf[4];
    {
        float (*Xs)[68] = (float (*)[68])smem;     // 128 x 68 f32 = 34816 B overlay
        const int xr = tid >> 1;                   // row 0..127
        const int xh = tid & 1;                    // half-row
        const float* xsrc = x + (size_t)(lb * 128 + xr) * ND + n * D_DIM;
        #pragma unroll
        for (int j = 0; j < 8; ++j) {
            const int f4i = xh * 8 + j;
            *(float4*)&Xs[xr][4 * f4i] = *(const float4*)(xsrc + 4 * f4i);
        }
        __syncthreads();
        const int rl = wid * 32 + l31;
        #pragma unroll
        for (int kk = 0; kk < 4; ++kk) {
            float4 f1 = *(const float4*)&Xs[rl][16 * kk + 8 * h];
            float4 f2 = *(const float4*)&Xs[rl][16 * kk + 8 * h + 4];
            Xf[kk] = mk_frag(pkh2(f1.x, f1.y), pkh2(f1.z, f1.w),
                             pkh2(f2.x, f2.y), pkh2(f2.z, f2.w));
        }
        __syncthreads();   // protect Xs before buf0 staging overwrites it
    }

    // ---- stage tile 0 into buf 0, issue tile-1 load ----
    #pragma unroll
    for (int j = 0; j < 2; ++j) {
        uint16_t (*Ub)[72]  = (uint16_t (*)[72])(smem);
        uint32_t (*Ut2)[68] = (uint32_t (*)[68])(smem + 9216);
        *(uint2*)&Ub[2*r8 + 32*j][4*c] =
            make_uint2(pkh2(va[j].x, va[j].y), pkh2(va[j].z, va[j].w));
        *(uint2*)&Ub[2*r8 + 32*j + 1][4*c] =
            make_uint2(pkh2(vb[j].x, vb[j].y), pkh2(vb[j].z, vb[j].w));
        *(uint4*)&Ut2[r8 + 16*j][4*c] =
            make_uint4(pkh2(va[j].x, vb[j].x), pkh2(va[j].y, vb[j].y),
                       pkh2(va[j].z, vb[j].z), pkh2(va[j].w, vb[j].w));
    }
    load_tile(ubase, 1, r8, c, va, vb);
    __syncthreads();

    floatx16 F0, F1;   // F^T accumulators, d 0..31 / 32..63
    #pragma unroll
    for (int i = 0; i < 16; ++i) { F0[i] = 0.0f; F1[i] = 0.0f; }

    for (int ot = 0; ot < NT; ++ot) {
        const int b = ot & 1;
        uint16_t (*Ub)[72]   = (uint16_t (*)[72])(smem + b * BUF_STRIDE);
        const uint32_t* utp  = (const uint32_t*)(smem + b * BUF_STRIDE + 9216);
        uint16_t (*Ubn)[72]  = (uint16_t (*)[72])(smem + (b ^ 1) * BUF_STRIDE);
        uint32_t (*Ut2n)[68] = (uint32_t (*)[68])(smem + (b ^ 1) * BUF_STRIDE + 9216);

        // hoist GEMM1 A-frag reads (in-order DS: issue before the stage writes)
        half8 A0k[4], A1k[4];
        #pragma unroll
        for (int kk = 0; kk < 4; ++kk) {
            A0k[kk] = *(const half8*)&Ub[l31][16 * kk + 8 * h];
            A1k[kk] = *(const half8*)&Ub[32 + l31][16 * kk + 8 * h];
        }

        // stage next tile (regs hold tile ot+1) into the other buffer
        if (ot + 1 < NT) {
            #pragma unroll
            for (int j = 0; j < 2; ++j) {
                *(uint2*)&Ubn[2*r8 + 32*j][4*c] =
                    make_uint2(pkh2(va[j].x, va[j].y), pkh2(va[j].z, va[j].w));
                *(uint2*)&Ubn[2*r8 + 32*j + 1][4*c] =
                    make_uint2(pkh2(vb[j].x, vb[j].y), pkh2(vb[j].z, vb[j].w));
                *(uint4*)&Ut2n[r8 + 16*j][4*c] =
                    make_uint4(pkh2(va[j].x, vb[j].x), pkh2(va[j].y, vb[j].y),
                               pkh2(va[j].z, vb[j].z), pkh2(va[j].w, vb[j].w));
            }
        }
        // distance-2 global prefetch into the just-consumed registers
        if (ot + 2 < NT)
            load_tile(ubase, ot + 2, r8, c, va, vb);

        // ---- GEMM1: S^T = U * X^T   (M=o, N=l, K=d) ----
        floatx16 S0, S1;
        #pragma unroll
        for (int i = 0; i < 16; ++i) { S0[i] = 0.0f; S1[i] = 0.0f; }
        #pragma unroll
        for (int kk = 0; kk < 4; ++kk) {
            S0 = __builtin_amdgcn_mfma_f32_32x32x16_f16(A0k[kk], Xf[kk], S0, 0, 0, 0);
            S1 = __builtin_amdgcn_mfma_f32_32x32x16_f16(A1k[kk], Xf[kk], S1, 0, 0, 0);
        }

        // ---- sigmoid weights: packed-fp16 odd polynomial ----
        uint32_t P[16];
        #pragma unroll
        for (int m = 0; m < 8; ++m) P[m]     = psig(S0[2*m], S0[2*m+1]);
        #pragma unroll
        for (int m = 0; m < 8; ++m) P[8 + m] = psig(S1[2*m], S1[2*m+1]);

        // ---- GEMM2: F^T += U^T * W — shuffles hoisted ahead of MFMA chain ----
        uint32_t R[8];
        #pragma unroll
        for (int c2 = 0; c2 < 4; ++c2) {
            const uint32_t* Q = P + (c2 >> 1) * 8;
            const int t4 = (c2 & 1) * 4;
            R[2*c2]   = __shfl_xor(h ? Q[t4]     : Q[t4 + 2], 32);
            R[2*c2+1] = __shfl_xor(h ? Q[t4 + 1] : Q[t4 + 3], 32);
        }
        #pragma unroll
        for (int c2 = 0; c2 < 4; ++c2) {
            const uint32_t* Q = P + (c2 >> 1) * 8;
            const int t4 = (c2 & 1) * 4;
            half8 B = h ? mk_frag(R[2*c2], R[2*c2+1], Q[t4 + 2], Q[t4 + 3])
                        : mk_frag(Q[t4], Q[t4 + 1], R[2*c2], R[2*c2+1]);
            // A-frags: row-pair gather of Ut2 (banks (4(opb+k)+l31)%32: 2/bank = free)
            const int opb = 8 * c2 + 4 * h;
            uint32_t a0[4], a1[4];
            #pragma unroll
            for (int k = 0; k < 4; ++k) {
                a0[k] = utp[(opb + k) * 68 + l31];
                a1[k] = utp[(opb + k) * 68 + 32 + l31];
            }
            half8 A0 = mk_frag(a0[0], a0[1], a0[2], a0[3]);
            half8 A1 = mk_frag(a1[0], a1[1], a1[2], a1[3]);
            F0 = __builtin_amdgcn_mfma_f32_32x32x16_f16(A0, B, F0, 0, 0, 0);
            F1 = __builtin_amdgcn_mfma_f32_32x32x16_f16(A1, B, F1, 0, 0, 0);
        }
        __syncthreads();   // one barrier per tile: protects next-buf writes
    }

    // ---- epilogue: direct store, no cross-team reduction needed ----
    float* op = out + (size_t)lw * ND + n * D_DIM;
    #pragma unroll
    for (int q = 0; q < 4; ++q) {
        float4 a; a.x = F0[4*q]; a.y = F0[4*q+1]; a.z = F0[4*q+2]; a.w = F0[4*q+3];
        *(float4*)(op + 8*q + 4*h) = a;               // d 0..31
        float4 bq; bq.x = F1[4*q]; bq.y = F1[4*q+1]; bq.z = F1[4*q+2]; bq.w = F1[4*q+3];
        *(float4*)(op + 32 + 8*q + 4*h) = bq;         // d 32..63
    }
}

extern "C" void kernel_launch(void* const* d_in, const int* in_sizes, int n_in,
                              void* d_out, int out_size, void* d_ws, size_t ws_size,
                              hipStream_t stream)
{
    const float* x  = (const float*)d_in[0];
    const float* up = (const float*)d_in[1];
    float* out      = (float*)d_out;
    dim3 grid(N_DIM, L_DIM / 128);   // x = n (XCD affinity), y = L-tile of 128
    corr_kernel<<<grid, dim3(256), 0, stream>>>(x, up, out);
}